// Round 7
// baseline (3564.632 us; speedup 1.0000x reference)
//
#include <hip/hip_runtime.h>

constexpr int NUM_USER  = 100000;
constexpr int NUM_ITEM  = 50000;
constexpr int DIM       = 64;
constexpr int NUM_EDGES = 3200000;

constexpr int KPB   = 64;                             // keys per bucket
constexpr int NB_U  = (NUM_USER + KPB - 1) / KPB;     // 1563
constexpr int NB_I  = (NUM_ITEM + KPB - 1) / KPB;     // 782
constexpr int GA    = 256;                            // hist/partition grid
constexpr int CH    = NUM_EDGES / GA;                 // 12500 (exact)
constexpr int HKEY  = 32;                             // keys per agg half-block

// ---------------------------------------------------------------------------
// bf16 helpers
// ---------------------------------------------------------------------------
__device__ __forceinline__ float bf2f(unsigned short u) {
  union { unsigned int i; float f; } v; v.i = (unsigned int)u << 16; return v.f;
}
__device__ __forceinline__ unsigned short f2bf(float x) {
  union { float f; unsigned int i; } v; v.f = x;
  unsigned int r = v.i + 0x7FFFu + ((v.i >> 16) & 1u);
  return (unsigned short)(r >> 16);
}

// ---------------------------------------------------------------------------
// Index dtype detection (int64 buffers have all-zero high words).
// ---------------------------------------------------------------------------
__global__ void k_detect(const void* eu, const void* ei, int* flag) {
  if (threadIdx.x == 0 && blockIdx.x == 0) {
    const int* a = (const int*)eu;
    const int* b = (const int*)ei;
    int any = 0;
    for (int i = 1; i < 64; i += 2) { any |= a[i]; any |= b[i]; }
    *flag = (any == 0) ? 1 : 0;  // 1 => int64 layout
  }
}

__device__ __forceinline__ int idx_at(const void* p, int e, int is64) {
  return is64 ? ((const int*)p)[2 * e] : ((const int*)p)[e];
}

// ---------------------------------------------------------------------------
// f32 -> bf16 tables.
// user16: linear rows of 64 bf16.
// fused : per item row of 128 bf16, dim-interleaved [item_l, agg_l]; cvt
//         writes even slots, k_agg_item writes odd slots.
// ---------------------------------------------------------------------------
__global__ void k_cvt_user(const float* __restrict__ ue,
                           unsigned short* __restrict__ u16) {
  const int n4 = NUM_USER * DIM / 4;
  for (int t = blockIdx.x * blockDim.x + threadIdx.x; t < n4;
       t += gridDim.x * blockDim.x) {
    const float4 v = ((const float4*)ue)[t];
    ushort4 o;
    o.x = f2bf(v.x); o.y = f2bf(v.y); o.z = f2bf(v.z); o.w = f2bf(v.w);
    ((ushort4*)u16)[t] = o;
  }
}

__global__ void k_cvt_item(const float* __restrict__ ie,
                           unsigned short* __restrict__ fused) {
  const int n4 = NUM_ITEM * DIM / 4;
  for (int t = blockIdx.x * blockDim.x + threadIdx.x; t < n4;
       t += gridDim.x * blockDim.x) {
    const float4 v = ((const float4*)ie)[t];
    const int g = t * 4;
    const int row = g >> 6, l = g & 63;
    const size_t base = (size_t)row * 128 + 2 * l;
    fused[base + 0] = f2bf(v.x);
    fused[base + 2] = f2bf(v.y);
    fused[base + 4] = f2bf(v.z);
    fused[base + 6] = f2bf(v.w);
  }
}

// ---------------------------------------------------------------------------
// Bucket histogram: LDS-privatized, per-block partial flush (no fp atomics).
// partials overlays the pairs buffer (used before pairs are written).
// ---------------------------------------------------------------------------
__global__ void k_hist_part(const void* eu_p, const void* ei_p,
                            const int* __restrict__ flag,
                            int* __restrict__ partials) {
  __shared__ int hu[NB_U];
  __shared__ int hi_[NB_I];
  for (int t = threadIdx.x; t < NB_U; t += blockDim.x) hu[t] = 0;
  for (int t = threadIdx.x; t < NB_I; t += blockDim.x) hi_[t] = 0;
  __syncthreads();
  const int is64 = *flag;
  const int b = blockIdx.x;
  const int lo = b * CH, hiE = lo + CH;
  for (int e = lo + threadIdx.x; e < hiE; e += blockDim.x) {
    atomicAdd(&hu[idx_at(eu_p, e, is64) >> 6], 1);
    atomicAdd(&hi_[idx_at(ei_p, e, is64) >> 6], 1);
  }
  __syncthreads();
  int* pu = partials;
  int* pi = partials + (size_t)NB_U * GA;
  for (int t = threadIdx.x; t < NB_U; t += blockDim.x) pu[(size_t)t * GA + b] = hu[t];
  for (int t = threadIdx.x; t < NB_I; t += blockDim.x) pi[(size_t)t * GA + b] = hi_[t];
}

__global__ void k_hist_reduce(const int* __restrict__ partials,
                              int* __restrict__ gcnt_u, int* __restrict__ gcnt_i) {
  const int k = blockIdx.x * blockDim.x + threadIdx.x;
  if (k >= NB_U + NB_I) return;
  const int* base = (k < NB_U) ? partials + (size_t)k * GA
                               : partials + (size_t)NB_U * GA + (size_t)(k - NB_U) * GA;
  int s = 0;
  for (int b = 0; b < GA; ++b) s += base[b];
  if (k < NB_U) gcnt_u[k] = s;
  else          gcnt_i[k - NB_U] = s;
}

// ---------------------------------------------------------------------------
// Exclusive scans of bucket counts
// ---------------------------------------------------------------------------
__device__ void scan_body(const int* __restrict__ in, int* __restrict__ out,
                          int* __restrict__ cur, int n) {
  __shared__ int part[1024];
  const int t = threadIdx.x;
  const int chunk = (n + 1023) >> 10;
  const int lo = min(t * chunk, n);
  const int hi = min(lo + chunk, n);
  int s = 0;
  for (int i = lo; i < hi; ++i) s += in[i];
  part[t] = s;
  __syncthreads();
  for (int d = 1; d < 1024; d <<= 1) {
    int v = (t >= d) ? part[t - d] : 0;
    __syncthreads();
    part[t] += v;
    __syncthreads();
  }
  int run = (t == 0) ? 0 : part[t - 1];
  for (int i = lo; i < hi; ++i) {
    int v = in[i];
    out[i] = run; cur[i] = run; run += v;
  }
  if (t == 1023) out[n] = part[1023];
}

__global__ void k_scan2(const int* cu, int* bu, int* curu,
                        const int* ci, int* bi, int* curi) {
  if (blockIdx.x == 0) scan_body(cu, bu, curu, NB_U);
  else                 scan_body(ci, bi, curi, NB_I);
}

// ---------------------------------------------------------------------------
// Partition edges into bucket-grouped packed pairs (local_key<<17 | value).
// ---------------------------------------------------------------------------
__global__ void k_part(const void* key_p, const void* val_p,
                       const int* __restrict__ flag,
                       int* gcur, unsigned int* __restrict__ pairs, int NB) {
  __shared__ int hist[NB_U];
  __shared__ int base[NB_U];
  for (int t = threadIdx.x; t < NB; t += blockDim.x) hist[t] = 0;
  __syncthreads();
  const int is64 = *flag;
  const int blk = blockIdx.x;
  const int lo = blk * CH, hiE = lo + CH;
  for (int e = lo + threadIdx.x; e < hiE; e += blockDim.x)
    atomicAdd(&hist[idx_at(key_p, e, is64) >> 6], 1);
  __syncthreads();
  for (int t = threadIdx.x; t < NB; t += blockDim.x) {
    const int h = hist[t];
    base[t] = h ? atomicAdd(&gcur[t], h) : 0;
    hist[t] = 0;  // reuse as in-block cursor
  }
  __syncthreads();
  for (int e = lo + threadIdx.x; e < hiE; e += blockDim.x) {
    const int k = idx_at(key_p, e, is64);
    const int v = idx_at(val_p, e, is64);
    const int bkt = k >> 6;
    const int pos = base[bkt] + atomicAdd(&hist[bkt], 1);
    pairs[pos] = ((unsigned)(k & 63) << 17) | (unsigned)v;
  }
}

// ---------------------------------------------------------------------------
// Bucket aggregation, dir-I. 2 blocks per bucket (half = blockIdx&1 owns 32
// local keys). Direct LDS f32 accumulation via native ds_add_f32
// (unsafeAtomicAdd). Two pairs per wave-iter: half h of the wave handles pair
// j+2s+h; 32 lanes cover the 128B user row as dwords (2 bf16 each).
// acc padded to 65 to avoid even-bank 4-way conflicts.
// ---------------------------------------------------------------------------
__global__ __launch_bounds__(256, 8)
void k_agg_item(const unsigned int* __restrict__ user32,
                const unsigned int* __restrict__ pairs,
                const int* __restrict__ gbase_i,
                unsigned short* __restrict__ fused) {
  __shared__ float acc[HKEY][DIM + 1];   // 8.3 KB, pad -> odd stride
  __shared__ int cnt[HKEY];
  const int tid = threadIdx.x;
  const int lane = tid & 63;
  const int wid = tid >> 6;
  const int half = lane >> 5;
  const int c = lane & 31;
  for (int t = tid; t < HKEY * (DIM + 1); t += 256)
    ((float*)acc)[t] = 0.f;
  if (tid < HKEY) cnt[tid] = 0;
  __syncthreads();
  const int bucket = blockIdx.x >> 1;
  const int key0 = (blockIdx.x & 1) * HKEY;
  const int lo = gbase_i[bucket], hi = gbase_i[bucket + 1];

  for (int j = lo + wid * 4; j < hi; j += 16) {
#pragma unroll
    for (int s = 0; s < 2; ++s) {
      const int jj = j + 2 * s + half;
      bool v = jj < hi;
      int k = 0; unsigned w = 0;
      if (v) {
        const unsigned p = pairs[jj];
        k = (int)(p >> 17) - key0;
        v = (unsigned)k < (unsigned)HKEY;
        if (v) w = user32[(size_t)(p & 0x1FFFF) * 32 + c];
      }
      if (v) {
        unsafeAtomicAdd(&acc[k][2 * c],     bf2f((unsigned short)(w & 0xFFFF)));
        unsafeAtomicAdd(&acc[k][2 * c + 1], bf2f((unsigned short)(w >> 16)));
        if (c == 0) atomicAdd(&cnt[k], 1);
      }
    }
  }
  __syncthreads();

  const int i0 = bucket * KPB + key0;
  for (int r = wid; r < HKEY; r += 4) {
    const int item = i0 + r;
    if (item < NUM_ITEM) {
      const float cdiv = fmaxf((float)cnt[r], 1.f);
      fused[(size_t)item * 128 + 2 * lane + 1] = f2bf(acc[r][lane] / cdiv);
    }
  }
}

// ---------------------------------------------------------------------------
// Bucket aggregation, dir-U: full wave per pair (lane = dim, 256B row),
// 4-wide ILP, direct LDS accumulation into two 32x64 f32 banks.
// ---------------------------------------------------------------------------
__global__ __launch_bounds__(256, 8)
void k_agg_user(const unsigned int* __restrict__ fused32,
                const unsigned int* __restrict__ pairs,
                const int* __restrict__ gbase_u,
                float* __restrict__ out0, float* __restrict__ out1) {
  __shared__ float a0[HKEY][DIM];   // 8 KB
  __shared__ float a1[HKEY][DIM];   // 8 KB
  __shared__ int cnt[HKEY];
  const int tid = threadIdx.x;
  const int lane = tid & 63;
  const int wid = tid >> 6;
  for (int t = tid; t < HKEY * DIM; t += 256) {
    ((float*)a0)[t] = 0.f;
    ((float*)a1)[t] = 0.f;
  }
  if (tid < HKEY) cnt[tid] = 0;
  __syncthreads();
  const int bucket = blockIdx.x >> 1;
  const int key0 = (blockIdx.x & 1) * HKEY;
  const int lo = gbase_u[bucket], hi = gbase_u[bucket + 1];

  for (int j = lo + wid * 4; j < hi; j += 16) {
    const int m = min(4, hi - j);
    unsigned w[4]; int k[4]; bool val[4];
#pragma unroll
    for (int q = 0; q < 4; ++q) {
      val[q] = false; k[q] = 0; w[q] = 0;
      if (q < m) {
        const unsigned p = pairs[j + q];
        const int kk = (int)(p >> 17) - key0;
        if ((unsigned)kk < (unsigned)HKEY) {
          val[q] = true; k[q] = kk;
          w[q] = fused32[(size_t)(p & 0x1FFFF) * DIM + lane];
        }
      }
    }
#pragma unroll
    for (int q = 0; q < 4; ++q) if (val[q]) {
      unsafeAtomicAdd(&a0[k[q]][lane], bf2f((unsigned short)(w[q] & 0xFFFF)));
      unsafeAtomicAdd(&a1[k[q]][lane], bf2f((unsigned short)(w[q] >> 16)));
      if (lane == 0) atomicAdd(&cnt[k[q]], 1);
    }
  }
  __syncthreads();

  const int u0 = bucket * KPB + key0;
  for (int r = wid; r < HKEY; r += 4) {
    const int u = u0 + r;
    if (u < NUM_USER) {
      const float inv = 1.0f / fmaxf((float)cnt[r], 1.f);
      out0[(size_t)u * DIM + lane] = a0[r][lane] * inv;
      out1[(size_t)u * DIM + lane] = a1[r][lane] * inv;
    }
  }
}

// ---------------------------------------------------------------------------
// Fallback (round-0 atomic path) if ws too small.
// ---------------------------------------------------------------------------
__global__ void k_scatter1(const float* __restrict__ user_emb,
                           const float* __restrict__ item_emb,
                           const void* eu_p, const void* ei_p,
                           const int* __restrict__ flag,
                           float* out0, float* item_sum,
                           float* cnt_user, float* cnt_item) {
  const int is64 = *flag;
  const int lane = threadIdx.x & (DIM - 1);
  const int sub  = threadIdx.x >> 6;
  const int epb  = blockDim.x >> 6;
  for (int e = blockIdx.x * epb + sub; e < NUM_EDGES; e += gridDim.x * epb) {
    const int eu = idx_at(eu_p, e, is64);
    const int ei = idx_at(ei_p, e, is64);
    atomicAdd(&out0[eu * DIM + lane], item_emb[ei * DIM + lane]);
    atomicAdd(&item_sum[ei * DIM + lane], user_emb[eu * DIM + lane]);
    if (lane == 0) {
      atomicAdd(&cnt_user[eu], 1.0f);
      atomicAdd(&cnt_item[ei], 1.0f);
    }
  }
}

__global__ void k_div_item(float* item_sum, const float* __restrict__ cnt_item) {
  const int n = NUM_ITEM * DIM;
  for (int t = blockIdx.x * blockDim.x + threadIdx.x; t < n;
       t += gridDim.x * blockDim.x)
    item_sum[t] /= fmaxf(cnt_item[t >> 6], 1.0f);
}

__global__ void k_scatter2(const float* __restrict__ item_agg,
                           const void* eu_p, const void* ei_p,
                           const int* __restrict__ flag, float* out1) {
  const int is64 = *flag;
  const int lane = threadIdx.x & (DIM - 1);
  const int sub  = threadIdx.x >> 6;
  const int epb  = blockDim.x >> 6;
  for (int e = blockIdx.x * epb + sub; e < NUM_EDGES; e += gridDim.x * epb) {
    const int eu = idx_at(eu_p, e, is64);
    const int ei = idx_at(ei_p, e, is64);
    atomicAdd(&out1[eu * DIM + lane], item_agg[ei * DIM + lane]);
  }
}

__global__ void k_finalize(float* out0, float* out1,
                           const float* __restrict__ cnt_user) {
  const int n = NUM_USER * DIM;
  for (int t = blockIdx.x * blockDim.x + threadIdx.x; t < n;
       t += gridDim.x * blockDim.x) {
    const float c = fmaxf(cnt_user[t >> 6], 1.0f);
    out0[t] /= c;
    out1[t] /= c;
  }
}

// ---------------------------------------------------------------------------
extern "C" void kernel_launch(void* const* d_in, const int* in_sizes, int n_in,
                              void* d_out, int out_size, void* d_ws, size_t ws_size,
                              hipStream_t stream) {
  const float* user_emb = (const float*)d_in[0];
  const float* item_emb = (const float*)d_in[1];
  const void*  eu_p     = d_in[2];
  const void*  ei_p     = d_in[3];

  float* out0 = (float*)d_out;
  float* out1 = out0 + (size_t)NUM_USER * DIM;

  // Workspace layout (u32 units), ~38.4 MB (proven available in R2-R6)
  const size_t o_pairs   = 0;                                    // 3.2M u32 (+partials overlay)
  const size_t o_user16  = o_pairs + NUM_EDGES;                  // 3.2M u32
  const size_t o_fused   = o_user16 + (size_t)NUM_USER * DIM / 2;// 3.2M u32
  const size_t o_gcnt_u  = o_fused + (size_t)NUM_ITEM * 128 / 2;
  const size_t o_gbase_u = o_gcnt_u + NB_U;
  const size_t o_gcur_u  = o_gbase_u + NB_U + 1;
  const size_t o_gcnt_i  = o_gcur_u + NB_U;
  const size_t o_gbase_i = o_gcnt_i + NB_I;
  const size_t o_gcur_i  = o_gbase_i + NB_I + 1;
  const size_t o_flag    = o_gcur_i + NB_I;
  const size_t need_bytes = (o_flag + 1) * 4;

  int* wsi = (int*)d_ws;
  float* wsf = (float*)d_ws;

  if (ws_size >= need_bytes) {
    unsigned int* pairs    = (unsigned int*)(wsi + o_pairs);
    int*          partials = wsi + o_pairs;                       // overlay
    unsigned short* user16 = (unsigned short*)(wsi + o_user16);
    unsigned int* user32   = (unsigned int*)(wsi + o_user16);
    unsigned short* fused  = (unsigned short*)(wsi + o_fused);
    unsigned int* fused32  = (unsigned int*)(wsi + o_fused);
    int* gcnt_u  = wsi + o_gcnt_u;
    int* gbase_u = wsi + o_gbase_u;
    int* gcur_u  = wsi + o_gcur_u;
    int* gcnt_i  = wsi + o_gcnt_i;
    int* gbase_i = wsi + o_gbase_i;
    int* gcur_i  = wsi + o_gcur_i;
    int* flag    = wsi + o_flag;

    k_detect<<<1, 64, 0, stream>>>(eu_p, ei_p, flag);
    k_hist_part<<<GA, 512, 0, stream>>>(eu_p, ei_p, flag, partials);
    k_hist_reduce<<<(NB_U + NB_I + 255) / 256, 256, 0, stream>>>(partials,
                                                                 gcnt_u, gcnt_i);
    k_scan2<<<2, 1024, 0, stream>>>(gcnt_u, gbase_u, gcur_u,
                                    gcnt_i, gbase_i, gcur_i);
    k_cvt_user<<<1024, 256, 0, stream>>>(user_emb, user16);
    k_cvt_item<<<512, 256, 0, stream>>>(item_emb, fused);

    // direction I: group by item, aggregate user embeddings -> fused odd slots
    k_part<<<GA, 512, 0, stream>>>(ei_p, eu_p, flag, gcur_i, pairs, NB_I);
    k_agg_item<<<NB_I * 2, 256, 0, stream>>>(user32, pairs, gbase_i, fused);

    // direction U: group by user, aggregate fused rows -> out0, out1
    k_part<<<GA, 512, 0, stream>>>(eu_p, ei_p, flag, gcur_u, pairs, NB_U);
    k_agg_user<<<NB_U * 2, 256, 0, stream>>>(fused32, pairs, gbase_u, out0, out1);
  } else {
    // fallback: round-0 atomic path (needs ~13 MB)
    float* item_sum = wsf;
    float* cnt_user = wsf + (size_t)NUM_ITEM * DIM;
    float* cnt_item = cnt_user + NUM_USER;
    int*   flag     = (int*)(cnt_item + NUM_ITEM);
    const size_t used = ((size_t)NUM_ITEM * DIM + NUM_USER + NUM_ITEM + 1) * 4;

    hipMemsetAsync(d_out, 0, (size_t)out_size * sizeof(float), stream);
    hipMemsetAsync(d_ws, 0, used, stream);
    k_detect<<<1, 64, 0, stream>>>(eu_p, ei_p, flag);
    k_scatter1<<<4096, 256, 0, stream>>>(user_emb, item_emb, eu_p, ei_p, flag,
                                         out0, item_sum, cnt_user, cnt_item);
    k_div_item<<<2048, 256, 0, stream>>>(item_sum, cnt_item);
    k_scatter2<<<4096, 256, 0, stream>>>(item_sum, eu_p, ei_p, flag, out1);
    k_finalize<<<2048, 256, 0, stream>>>(out0, out1, cnt_user);
  }
}

// Round 8
// 297.840 us; speedup vs baseline: 11.9683x; 11.9683x over previous
//
#include <hip/hip_runtime.h>
#include <hip/hip_fp16.h>

constexpr int NUM_USER  = 100000;
constexpr int NUM_ITEM  = 50000;
constexpr int DIM       = 64;
constexpr int NUM_EDGES = 3200000;

constexpr int KPB   = 64;                             // keys per bucket
constexpr int NB_U  = (NUM_USER + KPB - 1) / KPB;     // 1563
constexpr int NB_I  = (NUM_ITEM + KPB - 1) / KPB;     // 782
constexpr int GA    = 256;                            // hist/partition grid
constexpr int CH    = NUM_EDGES / GA;                 // 12500 (exact)
constexpr int HKEY  = 32;                             // keys per agg half-block
constexpr int CHUNK = 4096;                           // values per LDS-CSR chunk

// ---------------------------------------------------------------------------
// packed-f16 helpers
// ---------------------------------------------------------------------------
__device__ __forceinline__ __half2 u2h(unsigned u) {
  union { unsigned u; __half2 h; } v; v.u = u; return v.h;
}
__device__ __forceinline__ unsigned h2u(__half2 h) {
  union { __half2 h; unsigned u; } v; v.h = h; return v.u;
}

// ---------------------------------------------------------------------------
// Index dtype detection (int64 buffers have all-zero high words).
// ---------------------------------------------------------------------------
__global__ void k_detect(const void* eu, const void* ei, int* flag) {
  if (threadIdx.x == 0 && blockIdx.x == 0) {
    const int* a = (const int*)eu;
    const int* b = (const int*)ei;
    int any = 0;
    for (int i = 1; i < 64; i += 2) { any |= a[i]; any |= b[i]; }
    *flag = (any == 0) ? 1 : 0;  // 1 => int64 layout
  }
}

__device__ __forceinline__ int idx_at(const void* p, int e, int is64) {
  return is64 ? ((const int*)p)[2 * e] : ((const int*)p)[e];
}

// ---------------------------------------------------------------------------
// f32 -> packed-f16 tables.
// user32: per user row = 32 dwords, dword c = f16 dims (2c, 2c+1).
// fused : per item row = 64 dwords; dword 2c = item f16 dims (2c,2c+1),
//         dword 2c+1 = agg f16 dims (2c,2c+1) [written by k_agg_item].
// ---------------------------------------------------------------------------
__global__ void k_cvt_user(const float* __restrict__ ue,
                           unsigned* __restrict__ u32) {
  const int n = NUM_USER * 32;
  for (int t = blockIdx.x * blockDim.x + threadIdx.x; t < n;
       t += gridDim.x * blockDim.x) {
    const float2 v = ((const float2*)ue)[t];
    u32[t] = h2u(__floats2half2_rn(v.x, v.y));
  }
}

__global__ void k_cvt_item(const float* __restrict__ ie,
                           unsigned* __restrict__ fused) {
  const int n = NUM_ITEM * 32;
  for (int t = blockIdx.x * blockDim.x + threadIdx.x; t < n;
       t += gridDim.x * blockDim.x) {
    const float2 v = ((const float2*)ie)[t];
    const int row = t >> 5, c = t & 31;
    fused[(size_t)row * 64 + 2 * c] = h2u(__floats2half2_rn(v.x, v.y));
  }
}

// ---------------------------------------------------------------------------
// Bucket histogram: LDS-privatized, per-block partial flush (int atomics only).
// partials overlays the pairs buffer (used before pairs are written).
// ---------------------------------------------------------------------------
__global__ void k_hist_part(const void* eu_p, const void* ei_p,
                            const int* __restrict__ flag,
                            int* __restrict__ partials) {
  __shared__ int hu[NB_U];
  __shared__ int hi_[NB_I];
  for (int t = threadIdx.x; t < NB_U; t += blockDim.x) hu[t] = 0;
  for (int t = threadIdx.x; t < NB_I; t += blockDim.x) hi_[t] = 0;
  __syncthreads();
  const int is64 = *flag;
  const int b = blockIdx.x;
  const int lo = b * CH, hiE = lo + CH;
  for (int e = lo + threadIdx.x; e < hiE; e += blockDim.x) {
    atomicAdd(&hu[idx_at(eu_p, e, is64) >> 6], 1);
    atomicAdd(&hi_[idx_at(ei_p, e, is64) >> 6], 1);
  }
  __syncthreads();
  int* pu = partials;
  int* pi = partials + (size_t)NB_U * GA;
  for (int t = threadIdx.x; t < NB_U; t += blockDim.x) pu[(size_t)t * GA + b] = hu[t];
  for (int t = threadIdx.x; t < NB_I; t += blockDim.x) pi[(size_t)t * GA + b] = hi_[t];
}

__global__ void k_hist_reduce(const int* __restrict__ partials,
                              int* __restrict__ gcnt_u, int* __restrict__ gcnt_i) {
  const int k = blockIdx.x * blockDim.x + threadIdx.x;
  if (k >= NB_U + NB_I) return;
  const int* base = (k < NB_U) ? partials + (size_t)k * GA
                               : partials + (size_t)NB_U * GA + (size_t)(k - NB_U) * GA;
  int s = 0;
  for (int b = 0; b < GA; ++b) s += base[b];
  if (k < NB_U) gcnt_u[k] = s;
  else          gcnt_i[k - NB_U] = s;
}

// ---------------------------------------------------------------------------
// Exclusive scans of bucket counts
// ---------------------------------------------------------------------------
__device__ void scan_body(const int* __restrict__ in, int* __restrict__ out,
                          int* __restrict__ cur, int n) {
  __shared__ int part[1024];
  const int t = threadIdx.x;
  const int chunk = (n + 1023) >> 10;
  const int lo = min(t * chunk, n);
  const int hi = min(lo + chunk, n);
  int s = 0;
  for (int i = lo; i < hi; ++i) s += in[i];
  part[t] = s;
  __syncthreads();
  for (int d = 1; d < 1024; d <<= 1) {
    int v = (t >= d) ? part[t - d] : 0;
    __syncthreads();
    part[t] += v;
    __syncthreads();
  }
  int run = (t == 0) ? 0 : part[t - 1];
  for (int i = lo; i < hi; ++i) {
    int v = in[i];
    out[i] = run; cur[i] = run; run += v;
  }
  if (t == 1023) out[n] = part[1023];
}

__global__ void k_scan2(const int* cu, int* bu, int* curu,
                        const int* ci, int* bi, int* curi) {
  if (blockIdx.x == 0) scan_body(cu, bu, curu, NB_U);
  else                 scan_body(ci, bi, curi, NB_I);
}

// ---------------------------------------------------------------------------
// Partition edges into bucket-grouped packed pairs (local_key<<17 | value).
// ---------------------------------------------------------------------------
__global__ void k_part(const void* key_p, const void* val_p,
                       const int* __restrict__ flag,
                       int* gcur, unsigned int* __restrict__ pairs, int NB) {
  __shared__ int hist[NB_U];
  __shared__ int base[NB_U];
  for (int t = threadIdx.x; t < NB; t += blockDim.x) hist[t] = 0;
  __syncthreads();
  const int is64 = *flag;
  const int blk = blockIdx.x;
  const int lo = blk * CH, hiE = lo + CH;
  for (int e = lo + threadIdx.x; e < hiE; e += blockDim.x)
    atomicAdd(&hist[idx_at(key_p, e, is64) >> 6], 1);
  __syncthreads();
  for (int t = threadIdx.x; t < NB; t += blockDim.x) {
    const int h = hist[t];
    base[t] = h ? atomicAdd(&gcur[t], h) : 0;
    hist[t] = 0;  // reuse as in-block cursor
  }
  __syncthreads();
  for (int e = lo + threadIdx.x; e < hiE; e += blockDim.x) {
    const int k = idx_at(key_p, e, is64);
    const int v = idx_at(val_p, e, is64);
    const int bkt = k >> 6;
    const int pos = base[bkt] + atomicAdd(&hist[bkt], 1);
    pairs[pos] = ((unsigned)(k & 63) << 17) | (unsigned)v;
  }
}

// ---------------------------------------------------------------------------
// Bucket aggregation, dir-I. 2 blocks per bucket (half-bucket owns 32 local
// keys). LDS-CSR sort (int atomics, proven fast), then register accumulation
// in packed f16 (v_pk_add_f16): 2 pairs per wave (32 lanes/pair, lane = dim
// pair), 4-wide ILP. Epilogue combines wave halves via shfl_xor(32).
// ---------------------------------------------------------------------------
__global__ __launch_bounds__(256, 8)
void k_agg_item(const unsigned* __restrict__ user32,
                const unsigned int* __restrict__ pairs,
                const int* __restrict__ gbase_i,
                unsigned* __restrict__ fused) {
  __shared__ int sorted[CHUNK];
  __shared__ int hist[HKEY], base[HKEY], cur[HKEY];
  const int tid = threadIdx.x;
  const int lane = tid & 63;
  const int wid = tid >> 6;
  const int half = lane >> 5;
  const int c = lane & 31;
  const int bucket = blockIdx.x >> 1;
  const int key0 = (blockIdx.x & 1) * HKEY;
  const int lo = gbase_i[bucket], hi = gbase_i[bucket + 1];

  unsigned s[8]; int cnt[8];
#pragma unroll
  for (int r = 0; r < 8; ++r) { s[r] = 0u; cnt[r] = 0; }

  for (int clo = lo; clo < hi; clo += CHUNK) {
    const int csz = min(CHUNK, hi - clo);
    if (tid < HKEY) hist[tid] = 0;
    __syncthreads();
    for (int j = tid; j < csz; j += 256) {
      const int k = (int)(pairs[clo + j] >> 17) - key0;
      if ((unsigned)k < HKEY) atomicAdd(&hist[k], 1);
    }
    __syncthreads();
    if (tid < HKEY) {
      int b = 0;
      for (int q = 0; q < tid; ++q) b += hist[q];
      base[tid] = b; cur[tid] = b;
    }
    __syncthreads();
    for (int j = tid; j < csz; j += 256) {
      const unsigned p = pairs[clo + j];
      const int k = (int)(p >> 17) - key0;
      if ((unsigned)k < HKEY) {
        const int slot = atomicAdd(&cur[k], 1);
        sorted[slot] = (int)(p & 0x1FFFF);
      }
    }
    __syncthreads();
#pragma unroll
    for (int r = 0; r < 8; ++r) {
      const int key = wid * 8 + r;
      const int jlo = base[key], jhi = cur[key];
      cnt[r] += jhi - jlo;
      for (int j = jlo; j < jhi; j += 8) {
        unsigned w[4];
#pragma unroll
        for (int q = 0; q < 4; ++q) {
          const int jj = j + 2 * q + half;
          w[q] = (jj < jhi) ? user32[(size_t)sorted[jj] * 32 + c] : 0u;
        }
#pragma unroll
        for (int q = 0; q < 4; ++q)
          s[r] = h2u(__hadd2(u2h(s[r]), u2h(w[q])));
      }
    }
    __syncthreads();
  }

  const int i0 = bucket * KPB + key0;
#pragma unroll
  for (int r = 0; r < 8; ++r) {
    const unsigned o = (unsigned)__shfl_xor((int)s[r], 32);
    const __half2 tot = __hadd2(u2h(s[r]), u2h(o));
    const int item = i0 + wid * 8 + r;
    if (half == 0 && item < NUM_ITEM) {
      const float inv = 1.0f / fmaxf((float)cnt[r], 1.f);
      fused[(size_t)item * 64 + 2 * c + 1] =
          h2u(__floats2half2_rn(__low2float(tot) * inv, __high2float(tot) * inv));
    }
  }
}

// ---------------------------------------------------------------------------
// Bucket aggregation, dir-U: same structure; lane loads uint2 (item-pair
// dword + agg-pair dword) per pair, two packed-f16 accumulators.
// ---------------------------------------------------------------------------
__global__ __launch_bounds__(256, 8)
void k_agg_user(const unsigned* __restrict__ fused,
                const unsigned int* __restrict__ pairs,
                const int* __restrict__ gbase_u,
                float* __restrict__ out0, float* __restrict__ out1) {
  __shared__ int sorted[CHUNK];
  __shared__ int hist[HKEY], base[HKEY], cur[HKEY];
  const int tid = threadIdx.x;
  const int lane = tid & 63;
  const int wid = tid >> 6;
  const int half = lane >> 5;
  const int c = lane & 31;
  const int bucket = blockIdx.x >> 1;
  const int key0 = (blockIdx.x & 1) * HKEY;
  const int lo = gbase_u[bucket], hi = gbase_u[bucket + 1];
  const uint2* fused2 = (const uint2*)fused;   // row = 32 uint2

  unsigned s0[8], s1[8]; int cnt[8];
#pragma unroll
  for (int r = 0; r < 8; ++r) { s0[r] = 0u; s1[r] = 0u; cnt[r] = 0; }

  for (int clo = lo; clo < hi; clo += CHUNK) {
    const int csz = min(CHUNK, hi - clo);
    if (tid < HKEY) hist[tid] = 0;
    __syncthreads();
    for (int j = tid; j < csz; j += 256) {
      const int k = (int)(pairs[clo + j] >> 17) - key0;
      if ((unsigned)k < HKEY) atomicAdd(&hist[k], 1);
    }
    __syncthreads();
    if (tid < HKEY) {
      int b = 0;
      for (int q = 0; q < tid; ++q) b += hist[q];
      base[tid] = b; cur[tid] = b;
    }
    __syncthreads();
    for (int j = tid; j < csz; j += 256) {
      const unsigned p = pairs[clo + j];
      const int k = (int)(p >> 17) - key0;
      if ((unsigned)k < HKEY) {
        const int slot = atomicAdd(&cur[k], 1);
        sorted[slot] = (int)(p & 0x1FFFF);
      }
    }
    __syncthreads();
#pragma unroll
    for (int r = 0; r < 8; ++r) {
      const int key = wid * 8 + r;
      const int jlo = base[key], jhi = cur[key];
      cnt[r] += jhi - jlo;
      for (int j = jlo; j < jhi; j += 8) {
        uint2 w[4];
#pragma unroll
        for (int q = 0; q < 4; ++q) {
          const int jj = j + 2 * q + half;
          w[q] = (jj < jhi) ? fused2[(size_t)sorted[jj] * 32 + c]
                            : make_uint2(0u, 0u);
        }
#pragma unroll
        for (int q = 0; q < 4; ++q) {
          s0[r] = h2u(__hadd2(u2h(s0[r]), u2h(w[q].x)));
          s1[r] = h2u(__hadd2(u2h(s1[r]), u2h(w[q].y)));
        }
      }
    }
    __syncthreads();
  }

  const int u0 = bucket * KPB + key0;
#pragma unroll
  for (int r = 0; r < 8; ++r) {
    const unsigned o0 = (unsigned)__shfl_xor((int)s0[r], 32);
    const unsigned o1 = (unsigned)__shfl_xor((int)s1[r], 32);
    const __half2 t0 = __hadd2(u2h(s0[r]), u2h(o0));
    const __half2 t1 = __hadd2(u2h(s1[r]), u2h(o1));
    const int u = u0 + wid * 8 + r;
    if (half == 0 && u < NUM_USER) {
      const float inv = 1.0f / fmaxf((float)cnt[r], 1.f);
      ((float2*)out0)[(size_t)u * 32 + c] =
          make_float2(__low2float(t0) * inv, __high2float(t0) * inv);
      ((float2*)out1)[(size_t)u * 32 + c] =
          make_float2(__low2float(t1) * inv, __high2float(t1) * inv);
    }
  }
}

// ---------------------------------------------------------------------------
// Fallback (round-0 atomic path) if ws too small.
// ---------------------------------------------------------------------------
__global__ void k_scatter1(const float* __restrict__ user_emb,
                           const float* __restrict__ item_emb,
                           const void* eu_p, const void* ei_p,
                           const int* __restrict__ flag,
                           float* out0, float* item_sum,
                           float* cnt_user, float* cnt_item) {
  const int is64 = *flag;
  const int lane = threadIdx.x & (DIM - 1);
  const int sub  = threadIdx.x >> 6;
  const int epb  = blockDim.x >> 6;
  for (int e = blockIdx.x * epb + sub; e < NUM_EDGES; e += gridDim.x * epb) {
    const int eu = idx_at(eu_p, e, is64);
    const int ei = idx_at(ei_p, e, is64);
    atomicAdd(&out0[eu * DIM + lane], item_emb[ei * DIM + lane]);
    atomicAdd(&item_sum[ei * DIM + lane], user_emb[eu * DIM + lane]);
    if (lane == 0) {
      atomicAdd(&cnt_user[eu], 1.0f);
      atomicAdd(&cnt_item[ei], 1.0f);
    }
  }
}

__global__ void k_div_item(float* item_sum, const float* __restrict__ cnt_item) {
  const int n = NUM_ITEM * DIM;
  for (int t = blockIdx.x * blockDim.x + threadIdx.x; t < n;
       t += gridDim.x * blockDim.x)
    item_sum[t] /= fmaxf(cnt_item[t >> 6], 1.0f);
}

__global__ void k_scatter2(const float* __restrict__ item_agg,
                           const void* eu_p, const void* ei_p,
                           const int* __restrict__ flag, float* out1) {
  const int is64 = *flag;
  const int lane = threadIdx.x & (DIM - 1);
  const int sub  = threadIdx.x >> 6;
  const int epb  = blockDim.x >> 6;
  for (int e = blockIdx.x * epb + sub; e < NUM_EDGES; e += gridDim.x * epb) {
    const int eu = idx_at(eu_p, e, is64);
    const int ei = idx_at(ei_p, e, is64);
    atomicAdd(&out1[eu * DIM + lane], item_agg[ei * DIM + lane]);
  }
}

__global__ void k_finalize(float* out0, float* out1,
                           const float* __restrict__ cnt_user) {
  const int n = NUM_USER * DIM;
  for (int t = blockIdx.x * blockDim.x + threadIdx.x; t < n;
       t += gridDim.x * blockDim.x) {
    const float c = fmaxf(cnt_user[t >> 6], 1.0f);
    out0[t] /= c;
    out1[t] /= c;
  }
}

// ---------------------------------------------------------------------------
extern "C" void kernel_launch(void* const* d_in, const int* in_sizes, int n_in,
                              void* d_out, int out_size, void* d_ws, size_t ws_size,
                              hipStream_t stream) {
  const float* user_emb = (const float*)d_in[0];
  const float* item_emb = (const float*)d_in[1];
  const void*  eu_p     = d_in[2];
  const void*  ei_p     = d_in[3];

  float* out0 = (float*)d_out;
  float* out1 = out0 + (size_t)NUM_USER * DIM;

  // Workspace layout (u32 units), ~38.4 MB (proven available R2-R7)
  const size_t o_pairs   = 0;                                    // 3.2M u32 (+partials overlay)
  const size_t o_user32  = o_pairs + NUM_EDGES;                  // 3.2M u32 (NU*32)
  const size_t o_fused   = o_user32 + (size_t)NUM_USER * 32;     // 3.2M u32 (NI*64)
  const size_t o_gcnt_u  = o_fused + (size_t)NUM_ITEM * 64;
  const size_t o_gbase_u = o_gcnt_u + NB_U;
  const size_t o_gcur_u  = o_gbase_u + NB_U + 1;
  const size_t o_gcnt_i  = o_gcur_u + NB_U;
  const size_t o_gbase_i = o_gcnt_i + NB_I;
  const size_t o_gcur_i  = o_gbase_i + NB_I + 1;
  const size_t o_flag    = o_gcur_i + NB_I;
  const size_t need_bytes = (o_flag + 1) * 4;

  int* wsi = (int*)d_ws;
  float* wsf = (float*)d_ws;

  if (ws_size >= need_bytes) {
    unsigned int* pairs    = (unsigned int*)(wsi + o_pairs);
    int*          partials = wsi + o_pairs;                       // overlay
    unsigned* user32 = (unsigned*)(wsi + o_user32);
    unsigned* fused  = (unsigned*)(wsi + o_fused);
    int* gcnt_u  = wsi + o_gcnt_u;
    int* gbase_u = wsi + o_gbase_u;
    int* gcur_u  = wsi + o_gcur_u;
    int* gcnt_i  = wsi + o_gcnt_i;
    int* gbase_i = wsi + o_gbase_i;
    int* gcur_i  = wsi + o_gcur_i;
    int* flag    = wsi + o_flag;

    k_detect<<<1, 64, 0, stream>>>(eu_p, ei_p, flag);
    k_hist_part<<<GA, 512, 0, stream>>>(eu_p, ei_p, flag, partials);
    k_hist_reduce<<<(NB_U + NB_I + 255) / 256, 256, 0, stream>>>(partials,
                                                                 gcnt_u, gcnt_i);
    k_scan2<<<2, 1024, 0, stream>>>(gcnt_u, gbase_u, gcur_u,
                                    gcnt_i, gbase_i, gcur_i);
    k_cvt_user<<<1024, 256, 0, stream>>>(user_emb, user32);
    k_cvt_item<<<512, 256, 0, stream>>>(item_emb, fused);

    // direction I: group by item, aggregate user embeddings -> fused odd dwords
    k_part<<<GA, 512, 0, stream>>>(ei_p, eu_p, flag, gcur_i, pairs, NB_I);
    k_agg_item<<<NB_I * 2, 256, 0, stream>>>(user32, pairs, gbase_i, fused);

    // direction U: group by user, aggregate fused rows -> out0, out1
    k_part<<<GA, 512, 0, stream>>>(eu_p, ei_p, flag, gcur_u, pairs, NB_U);
    k_agg_user<<<NB_U * 2, 256, 0, stream>>>(fused, pairs, gbase_u, out0, out1);
  } else {
    // fallback: round-0 atomic path (needs ~13 MB)
    float* item_sum = wsf;
    float* cnt_user = wsf + (size_t)NUM_ITEM * DIM;
    float* cnt_item = cnt_user + NUM_USER;
    int*   flag     = (int*)(cnt_item + NUM_ITEM);
    const size_t used = ((size_t)NUM_ITEM * DIM + NUM_USER + NUM_ITEM + 1) * 4;

    hipMemsetAsync(d_out, 0, (size_t)out_size * sizeof(float), stream);
    hipMemsetAsync(d_ws, 0, used, stream);
    k_detect<<<1, 64, 0, stream>>>(eu_p, ei_p, flag);
    k_scatter1<<<4096, 256, 0, stream>>>(user_emb, item_emb, eu_p, ei_p, flag,
                                         out0, item_sum, cnt_user, cnt_item);
    k_div_item<<<2048, 256, 0, stream>>>(item_sum, cnt_item);
    k_scatter2<<<4096, 256, 0, stream>>>(item_sum, eu_p, ei_p, flag, out1);
    k_finalize<<<2048, 256, 0, stream>>>(out0, out1, cnt_user);
  }
}